// Round 8
// baseline (735.250 us; speedup 1.0000x reference)
//
#include <hip/hip_runtime.h>

// Problem constants
#define BATCH 16
#define CDIM  256   // embedding dim / K of the GEMM
#define HDIM  64
#define WDIM  64
#define NQ    65536   // BATCH*HDIM*WDIM
#define NE    1024    // codebook size
#define BM    32      // queries per block in argmin kernel
#define KB    8       // k-rows staged per B tile (double-buffered)
#define SECW  512     // codes per section (2 sections)

// d_out layout (floats): [0]=loss, [1..16777216]=z_q_st, [16777217..16842752]=idx, [16842753]=perplexity
#define ZQ_OFF   1
#define IDX_OFF  16777217
#define PERP_OFF 16842753

// ws layout: ee float[1024] @0 ; hist int[1024] @4096 ; loss_part double[256] @8192 ; W_T float[256][1024] @16384
#define WS_EE_OFF    0
#define WS_HIST_OFF  4096
#define WS_LOSS_OFF  8192
#define WS_WT_OFF    16384

// ---- numpy-pairwise sum-of-squares over 128 contiguous floats (8-accumulator tree) ----
__device__ __forceinline__ float pw128_sq(const float* __restrict__ p) {
    float r[8];
#pragma unroll
    for (int j = 0; j < 8; j++) r[j] = __fmul_rn(p[j], p[j]);
#pragma unroll
    for (int i = 8; i < 128; i += 8) {
#pragma unroll
        for (int j = 0; j < 8; j++) r[j] = __fadd_rn(r[j], __fmul_rn(p[i + j], p[i + j]));
    }
    return __fadd_rn(__fadd_rn(__fadd_rn(r[0], r[1]), __fadd_rn(r[2], r[3])),
                     __fadd_rn(__fadd_rn(r[4], r[5]), __fadd_rn(r[6], r[7])));
}

// ---- k1: codebook norms (numpy-pairwise), zero hist + loss accumulators ----
__global__ void vq_prep(const float* __restrict__ W, float* __restrict__ ee,
                        int* __restrict__ hist, double* __restrict__ loss_part) {
    int t = blockIdx.x * 256 + threadIdx.x;   // 0..1023, grid=4
    hist[t] = 0;
    if (t < 256) loss_part[t] = 0.0;
    const float* p = W + (size_t)t * CDIM;
    ee[t] = __fadd_rn(pw128_sq(p), pw128_sq(p + 128));
}

// ---- k1b: transpose W [1024][256] -> W_T [256][1024] (bitwise copy, enables linear
//           global_load_lds staging of k-major B tiles in vq_argmin) ----
__global__ void vq_transpose(const float* __restrict__ W, float* __restrict__ WT) {
    __shared__ float T[64][65];               // +1 pad: transposed reads 2-way (free)
    const int e0 = (blockIdx.x & 15) * 64;
    const int k0 = (blockIdx.x >> 4) * 64;
    const int r  = threadIdx.x >> 4;          // 0..15
    const int c4 = threadIdx.x & 15;          // 0..15
#pragma unroll
    for (int s = 0; s < 4; s++) {
        float4 v = *(const float4*)(W + (size_t)(e0 + s * 16 + r) * CDIM + k0 + c4 * 4);
        T[s * 16 + r][c4 * 4 + 0] = v.x;
        T[s * 16 + r][c4 * 4 + 1] = v.y;
        T[s * 16 + r][c4 * 4 + 2] = v.z;
        T[s * 16 + r][c4 * 4 + 3] = v.w;
    }
    __syncthreads();
#pragma unroll
    for (int s = 0; s < 4; s++) {
        float4 o;
        o.x = T[c4 * 4 + 0][s * 16 + r];
        o.y = T[c4 * 4 + 1][s * 16 + r];
        o.z = T[c4 * 4 + 2][s * 16 + r];
        o.w = T[c4 * 4 + 3][s * 16 + r];
        *(float4*)(WT + (size_t)(k0 + s * 16 + r) * NE + e0 + c4 * 4) = o;
    }
}

// ---- k2: fused distance GEMM + argmin ----
// Structure: 2 code sections, acc[8][8]; B via global_load_lds double-buffered
// tiles (one barrier per kc). THE FIX THIS ROUND: A operands move from the
// scalar pipe (s_load shares lgkmcnt with ds_read -> compiler must drain
// lgkmcnt(0) every k-step, the ~33% idle in rounds 1-7) to vector broadcast
// global_load_dwordx4 (vmcnt-counted, L1/L2-hot), double-buffered in 8 NAMED
// float4s at 2-k-step granularity (group g+2 issued right after computing
// group g -> ~256cy cover vs ~200cy L2 latency). lgkmcnt is now pure-DS ->
// fine-grained waits. bestD/bestI live in LDS (redD/redI, RMW once per
// section) to keep live VGPR ~116 under the (256,2) 128-reg budget that
// round 7 proved allocates cleanly.
// FMA chain per (q,code) is k=0..255 ascending, identical rounding -> bit-exact.
__global__ __launch_bounds__(256, 2)
void vq_argmin(const float* __restrict__ z, const float* __restrict__ WT,
               const float* __restrict__ ee, float* __restrict__ out_idx,
               int* __restrict__ hist) {
    __shared__ __align__(16) float S[12288];  // 48 KB: A|Bs in [0,8192); redD/redI after
    __shared__ float zz_s[BM];
    __shared__ float tmp2[64];
    __shared__ float pD[BM][8];
    __shared__ int   pI[BM][8];

    float (*A)[BM]        = (float (*)[BM])S;             // [256][32] (prologue only)
    float (*Bs)[KB][SECW] = (float (*)[KB][SECW])S;       // [2][8][512] = 32 KB (main loop)
    float (*redD)[64]     = (float (*)[64])(S + 8192);    // [32][64] = 8 KB (persistent)
    int   (*redI)[64]     = (int   (*)[64])(S + 10240);   // [32][64] = 8 KB (persistent)

    const int t    = threadIdx.x;
    const int lane = t & 63;
    const int wv   = t >> 6;                            // wave id 0..3
    const int n0   = blockIdx.x * BM;
    const int b    = n0 >> 12;
    const int h    = (n0 >> 6) & 63;
    const int w0   = n0 & 63;                           // 0 or 32

    // ---- stage A: zf_tile[c][q] = z[b, c, h, w0+q]; coalesced float4 ----
    const float* zb = z + (size_t)b * (CDIM * HDIM * WDIM) + (size_t)h * WDIM + w0;
#pragma unroll
    for (int v = 0; v < 8; v++) {
        int idx4 = v * 256 + t;
        int c  = idx4 >> 3;
        int w4 = idx4 & 7;
        *(float4*)(&A[c][w4 * 4]) = *(const float4*)(zb + (size_t)c * (HDIM * WDIM) + w4 * 4);
    }
    __syncthreads();

    // ---- zz per query, replicating numpy pairwise (two 128-blocks, 8 accumulators) ----
    if (t < 64) {
        int q = t >> 1, base = (t & 1) * 128;
        float r[8];
#pragma unroll
        for (int j = 0; j < 8; j++) { float x = A[base + j][q]; r[j] = __fmul_rn(x, x); }
        for (int i = 8; i < 128; i += 8) {
#pragma unroll
            for (int j = 0; j < 8; j++) { float x = A[base + i + j][q]; r[j] = __fadd_rn(r[j], __fmul_rn(x, x)); }
        }
        tmp2[t] = __fadd_rn(__fadd_rn(__fadd_rn(r[0], r[1]), __fadd_rn(r[2], r[3])),
                            __fadd_rn(__fadd_rn(r[4], r[5]), __fadd_rn(r[6], r[7])));
    }
    __syncthreads();
    if (t < BM) zz_s[t] = __fadd_rn(tmp2[2 * t], tmp2[2 * t + 1]);

    const int tx = t & 63;               // 0..63: code-groups (2x4 codes each)
    const int q0 = wv * 8;               // 8 queries per wave
    const float* aq = zb + q0;           // A[k][q0+i] = aq[k*4096+i]; addr wave-uniform
                                         // but divergent-to-compiler -> broadcast vector load

    // stage one KB x 512 tile of W_T into Bs[nb]: 8 rows x 2 halves; 4 instrs/thread,
    // each wave-instr writes 1 KB contiguous (wave-uniform base + lane*16B)
    auto stage = [&](int ssec, int skc, int nb) {
#pragma unroll
        for (int v = 0; v < 4; v++) {
            const int s_  = v * 4 + wv;                  // 0..15
            const int r_  = s_ >> 1;                     // row 0..7 (uniform per wave)
            const int hf_ = s_ & 1;                      // half 0/1 (uniform per wave)
            const float* g_ = WT + (size_t)(skc * KB + r_) * NE + ssec * SECW + hf_ * 256 + lane * 4;
            __builtin_amdgcn_global_load_lds(
                (const __attribute__((address_space(1))) void*)g_,
                (__attribute__((address_space(3))) void*)(&Bs[nb][r_][hf_ * 256]),
                16, 0, 0);
        }
    };

// load A for k-steps K, K+1 into four named float4s (broadcast, vmcnt-counted)
#define LOADA2(K, X0, X1, X2, X3)                                   \
    {                                                               \
        const float* ap0_ = aq + (size_t)((K) & 255) * 4096;        \
        const float* ap1_ = aq + (size_t)(((K) + 1) & 255) * 4096;  \
        X0 = *(const float4*)ap0_;                                  \
        X1 = *(const float4*)(ap0_ + 4);                            \
        X2 = *(const float4*)ap1_;                                  \
        X3 = *(const float4*)(ap1_ + 4);                            \
    }

// compute k-steps K2, K2+1 of tile CUR from four named float4s (k-order sequential)
#define COMPUTE2(CUR, K2, A0, A1, A2, A3)                                      \
    {                                                                          \
        const float4 ba0 = *(const float4*)(&Bs[CUR][K2][tx * 4]);             \
        const float4 bb0 = *(const float4*)(&Bs[CUR][K2][256 + tx * 4]);       \
        float avv[8] = {A0.x, A0.y, A0.z, A0.w, A1.x, A1.y, A1.z, A1.w};       \
        float bvv[8] = {ba0.x, ba0.y, ba0.z, ba0.w, bb0.x, bb0.y, bb0.z, bb0.w};\
        _Pragma("unroll")                                                      \
        for (int i = 0; i < 8; i++)                                            \
            _Pragma("unroll")                                                  \
            for (int j = 0; j < 8; j++)                                        \
                acc[i][j] = __fmaf_rn(avv[i], bvv[j], acc[i][j]);              \
        const float4 ba1 = *(const float4*)(&Bs[CUR][(K2) + 1][tx * 4]);       \
        const float4 bb1 = *(const float4*)(&Bs[CUR][(K2) + 1][256 + tx * 4]); \
        float avw[8] = {A2.x, A2.y, A2.z, A2.w, A3.x, A3.y, A3.z, A3.w};       \
        float bvw[8] = {ba1.x, ba1.y, ba1.z, ba1.w, bb1.x, bb1.y, bb1.z, bb1.w};\
        _Pragma("unroll")                                                      \
        for (int i = 0; i < 8; i++)                                            \
            _Pragma("unroll")                                                  \
            for (int j = 0; j < 8; j++)                                        \
                acc[i][j] = __fmaf_rn(avw[i], bvw[j], acc[i][j]);              \
    }

    // A pipeline: two 2-k-step groups in named float4s (pure SSA, no arrays)
    float4 pA0, pA1, pA2, pA3, nA0, nA1, nA2, nA3;

    // prologue: tile (sec0,kc0) -> buf0; pA <- k{0,1}, nA <- k{2,3}
    stage(0, 0, 0);
    LOADA2(0, pA0, pA1, pA2, pA3)
    LOADA2(2, nA0, nA1, nA2, nA3)
    __syncthreads();   // zz_s visible + tile0 + pA/nA drained

    for (int sec = 0; sec < 2; sec++) {
        float acc[8][8];
#pragma unroll
        for (int i = 0; i < 8; i++)
#pragma unroll
            for (int j = 0; j < 8; j++) acc[i][j] = 0.0f;

        for (int kc = 0; kc < 32; kc++) {
            const int cur = kc & 1;
            // stage next B tile into the other buffer (drained by this kc's barrier)
            {
                int nkc = kc + 1, nsec = sec;
                if (nkc == 32) { nkc = 0; nsec++; }
                if (nsec < 2) stage(nsec, nkc, cur ^ 1);
            }
            const int kb = kc * KB;
            // 4 phases of 2 k-steps; refill the just-consumed group 2 steps ahead.
            // Entering invariant: pA={kb,kb+1}, nA={kb+2,kb+3} (wraps via &255
            // across kc and sec boundaries; A is section-independent).
            COMPUTE2(cur, 0, pA0, pA1, pA2, pA3)
            LOADA2(kb + 4, pA0, pA1, pA2, pA3)
            COMPUTE2(cur, 2, nA0, nA1, nA2, nA3)
            LOADA2(kb + 6, nA0, nA1, nA2, nA3)
            COMPUTE2(cur, 4, pA0, pA1, pA2, pA3)
            LOADA2(kb + 8, pA0, pA1, pA2, pA3)
            COMPUTE2(cur, 6, nA0, nA1, nA2, nA3)
            LOADA2(kb + 10, nA0, nA1, nA2, nA3)
            __syncthreads();   // all waves done with Bs[cur]; next tile + A groups drained
        }

        // epilogue: d = fl(fl(zz+ee) - 2m), running argmin vs LDS-resident best.
        // Thread-local e scan ascending (group a then b, sec0 before sec1) +
        // strict <  ==  reference first-min tie rule. One RMW per section.
        const int e0a = sec * SECW + tx * 4;
        const int e0b = e0a + 256;
        float4 eeA = *(const float4*)(ee + e0a);
        float4 eeB = *(const float4*)(ee + e0b);
        float eva[4] = {eeA.x, eeA.y, eeA.z, eeA.w};
        float evb[4] = {eeB.x, eeB.y, eeB.z, eeB.w};
#pragma unroll
        for (int i = 0; i < 8; i++) {
            float bd; int bi;
            if (sec == 0) { bd = 3.0e38f; bi = 0; }
            else          { bd = redD[q0 + i][tx]; bi = redI[q0 + i][tx]; }
            const float zzq = zz_s[q0 + i];
#pragma unroll
            for (int j = 0; j < 4; j++) {
                float s = __fadd_rn(zzq, eva[j]);
                float d = __fsub_rn(s, __fadd_rn(acc[i][j], acc[i][j]));
                if (d < bd) { bd = d; bi = e0a + j; }
            }
#pragma unroll
            for (int j = 0; j < 4; j++) {
                float s = __fadd_rn(zzq, evb[j]);
                float d = __fsub_rn(s, __fadd_rn(acc[i][4 + j], acc[i][4 + j]));
                if (d < bd) { bd = d; bi = e0b + j; }
            }
            redD[q0 + i][tx] = bd; redI[q0 + i][tx] = bi;
        }
    }
#undef COMPUTE2
#undef LOADA2

    // ---- cross-thread argmin reduce (lexicographic: min d, then min idx) ----
    __syncthreads();
    {
        int q = t >> 3, s8 = t & 7;
        float bd = redD[q][s8 * 8]; int bi = redI[q][s8 * 8];
#pragma unroll
        for (int u = 1; u < 8; u++) {
            float d2 = redD[q][s8 * 8 + u]; int i2 = redI[q][s8 * 8 + u];
            if (d2 < bd || (d2 == bd && i2 < bi)) { bd = d2; bi = i2; }
        }
        pD[q][s8] = bd; pI[q][s8] = bi;
    }
    __syncthreads();
    if (t < BM) {
        float bd = pD[t][0]; int bi = pI[t][0];
#pragma unroll
        for (int u = 1; u < 8; u++) {
            float d2 = pD[t][u]; int i2 = pI[t][u];
            if (d2 < bd || (d2 == bd && i2 < bi)) { bd = d2; bi = i2; }
        }
        out_idx[n0 + t] = (float)bi;
        atomicAdd(&hist[bi], 1);
    }
}

// ---- k4: gather z_q, straight-through output, loss partials ----
__global__ void vq_gather(const float* __restrict__ z, const float* __restrict__ W,
                          const float* __restrict__ idxf, float* __restrict__ zq_out,
                          double* __restrict__ loss_part) {
    const int gid = blockIdx.x * 256 + threadIdx.x;  // 0..4194303 (grid=16384)
    const int w4 = gid & 15;
    const int r  = gid >> 4;         // 0..262143
    const int h  = r & 63;
    const int c  = (r >> 6) & 255;
    const int b  = r >> 14;
    const size_t off = (((size_t)(b * CDIM + c) * HDIM + h) * WDIM) + w4 * 4;
    const float4 zp = *(const float4*)(z + off);
    const int n = b * 4096 + h * 64 + w4 * 4;

    float zpv[4] = {zp.x, zp.y, zp.z, zp.w};
    float ov[4];
    double ls = 0.0;
#pragma unroll
    for (int l = 0; l < 4; l++) {
        int idx = (int)idxf[n + l];
        float zq = W[(size_t)idx * CDIM + c];
        float t1 = __fsub_rn(zq, zpv[l]);       // fl(z_q - zp)
        ov[l] = __fadd_rn(zpv[l], t1);          // fl(zp + fl(z_q - zp))
        ls += (double)t1 * (double)t1;
    }
    float4 o = {ov[0], ov[1], ov[2], ov[3]};
    *(float4*)(zq_out + off) = o;

    // wave + block reduce, one atomic per block into 256 slots
#pragma unroll
    for (int s = 32; s > 0; s >>= 1) ls += __shfl_down(ls, s, 64);
    __shared__ double wsum[4];
    if ((threadIdx.x & 63) == 0) wsum[threadIdx.x >> 6] = ls;
    __syncthreads();
    if (threadIdx.x == 0) {
        double v = wsum[0] + wsum[1] + wsum[2] + wsum[3];
        atomicAdd(&loss_part[blockIdx.x & 255], v);
    }
}

// ---- k5: finalize loss + perplexity ----
__global__ void vq_final(const double* __restrict__ loss_part, const int* __restrict__ hist,
                         float* __restrict__ d_out) {
    __shared__ double s1[256], s2[256];
    const int t = threadIdx.x;
    double v = loss_part[t];
    double pv = 0.0;
#pragma unroll
    for (int j = 0; j < 4; j++) {
        int cnt = hist[t * 4 + j];
        double em = (double)cnt / 65536.0;
        pv += em * log(em + 1e-10);
    }
    s1[t] = v; s2[t] = pv;
    __syncthreads();
    for (int st = 128; st > 0; st >>= 1) {
        if (t < st) { s1[t] += s1[t + st]; s2[t] += s2[t + st]; }
        __syncthreads();
    }
    if (t == 0) {
        float m = (float)(s1[0] / 16777216.0);
        d_out[0] = 1.25f * m;                    // mean + 0.25*mean
        d_out[PERP_OFF] = (float)exp(-s2[0]);
    }
}

extern "C" void kernel_launch(void* const* d_in, const int* in_sizes, int n_in,
                              void* d_out, int out_size, void* d_ws, size_t ws_size,
                              hipStream_t stream) {
    const float* z = (const float*)d_in[0];
    const float* W = (const float*)d_in[1];
    float* out = (float*)d_out;

    float*  ee        = (float*)((char*)d_ws + WS_EE_OFF);
    int*    hist      = (int*)((char*)d_ws + WS_HIST_OFF);
    double* loss_part = (double*)((char*)d_ws + WS_LOSS_OFF);
    float*  WT        = (float*)((char*)d_ws + WS_WT_OFF);   // 1 MB k-major codebook

    vq_prep<<<4, 256, 0, stream>>>(W, ee, hist, loss_part);
    vq_transpose<<<64, 256, 0, stream>>>(W, WT);
    vq_argmin<<<NQ / BM, 256, 0, stream>>>(z, WT, ee, out + IDX_OFF, hist);
    vq_gather<<<(NQ * CDIM / 4) / 256, 256, 0, stream>>>(z, W, out + IDX_OFF, out + ZQ_OFF, loss_part);
    vq_final<<<1, 256, 0, stream>>>(loss_part, hist, out);
}

// Round 9
// 621.187 us; speedup vs baseline: 1.1836x; 1.1836x over previous
//
#include <hip/hip_runtime.h>

// Problem constants
#define BATCH 16
#define CDIM  256   // embedding dim / K of the GEMM
#define HDIM  64
#define WDIM  64
#define NQ    65536   // BATCH*HDIM*WDIM
#define NE    1024    // codebook size
#define BM    32      // queries per block in argmin kernel
#define KB    8       // k-rows staged per B tile (double-buffered)
#define SECW  512     // codes per section (2 sections)

// d_out layout (floats): [0]=loss, [1..16777216]=z_q_st, [16777217..16842752]=idx, [16842753]=perplexity
#define ZQ_OFF   1
#define IDX_OFF  16777217
#define PERP_OFF 16842753

// ws layout: ee float[1024] @0 ; hist int[1024] @4096 ; loss_part double[256] @8192 ; W_T float[256][1024] @16384
#define WS_EE_OFF    0
#define WS_HIST_OFF  4096
#define WS_LOSS_OFF  8192
#define WS_WT_OFF    16384

// ---- numpy-pairwise sum-of-squares over 128 contiguous floats (8-accumulator tree) ----
__device__ __forceinline__ float pw128_sq(const float* __restrict__ p) {
    float r[8];
#pragma unroll
    for (int j = 0; j < 8; j++) r[j] = __fmul_rn(p[j], p[j]);
#pragma unroll
    for (int i = 8; i < 128; i += 8) {
#pragma unroll
        for (int j = 0; j < 8; j++) r[j] = __fadd_rn(r[j], __fmul_rn(p[i + j], p[i + j]));
    }
    return __fadd_rn(__fadd_rn(__fadd_rn(r[0], r[1]), __fadd_rn(r[2], r[3])),
                     __fadd_rn(__fadd_rn(r[4], r[5]), __fadd_rn(r[6], r[7])));
}

// ---- k1: codebook norms (numpy-pairwise), zero hist + loss accumulators ----
__global__ void vq_prep(const float* __restrict__ W, float* __restrict__ ee,
                        int* __restrict__ hist, double* __restrict__ loss_part) {
    int t = blockIdx.x * 256 + threadIdx.x;   // 0..1023, grid=4
    hist[t] = 0;
    if (t < 256) loss_part[t] = 0.0;
    const float* p = W + (size_t)t * CDIM;
    ee[t] = __fadd_rn(pw128_sq(p), pw128_sq(p + 128));
}

// ---- k1b: transpose W [1024][256] -> W_T [256][1024] (bitwise copy, enables linear
//           global_load_lds staging of k-major B tiles in vq_argmin) ----
__global__ void vq_transpose(const float* __restrict__ W, float* __restrict__ WT) {
    __shared__ float T[64][65];               // +1 pad: transposed reads 2-way (free)
    const int e0 = (blockIdx.x & 15) * 64;
    const int k0 = (blockIdx.x >> 4) * 64;
    const int r  = threadIdx.x >> 4;          // 0..15
    const int c4 = threadIdx.x & 15;          // 0..15
#pragma unroll
    for (int s = 0; s < 4; s++) {
        float4 v = *(const float4*)(W + (size_t)(e0 + s * 16 + r) * CDIM + k0 + c4 * 4);
        T[s * 16 + r][c4 * 4 + 0] = v.x;
        T[s * 16 + r][c4 * 4 + 1] = v.y;
        T[s * 16 + r][c4 * 4 + 2] = v.z;
        T[s * 16 + r][c4 * 4 + 3] = v.w;
    }
    __syncthreads();
#pragma unroll
    for (int s = 0; s < 4; s++) {
        float4 o;
        o.x = T[c4 * 4 + 0][s * 16 + r];
        o.y = T[c4 * 4 + 1][s * 16 + r];
        o.z = T[c4 * 4 + 2][s * 16 + r];
        o.w = T[c4 * 4 + 3][s * 16 + r];
        *(float4*)(WT + (size_t)(k0 + s * 16 + r) * NE + e0 + c4 * 4) = o;
    }
}

// ---- k2: fused distance GEMM + argmin ----
// PURE-DS INNER LOOP. Rounds 1-7 plateaued at ~447us/67% VALUBusy because A
// came via s_load: SMEM shares lgkmcnt with ds_read but completes OUT OF
// ORDER, so every kc's first use forces lgkmcnt(0) draining all in-flight
// scalar loads (~300cy stall/kc). Fix: A's LDS tile stays PERSISTENT (own
// 32 KB region, not overlaid by Bs); av = two broadcast ds_read_b128 per
// k-step (same-address broadcast = conflict-free; DS completes in-order ->
// compiler's fine-grained lgkmcnt(N) pipelines it, same mechanism as the B
// path). No VGPR A-pipeline (that spilled in r2/r3/r8): av is 8 transient
// regs; est. live ~104 < the 128 budget that (256,2) proved clean in r7.
// LDS 68 KB -> 2 blocks/CU (measured occupancy was ~7 waves/CU anyway).
// FMA chain per (q,code) is k=0..255 ascending, identical rounding -> bit-exact.
__global__ __launch_bounds__(256, 2)
void vq_argmin(const float* __restrict__ z, const float* __restrict__ WT,
               const float* __restrict__ ee, float* __restrict__ out_idx,
               int* __restrict__ hist) {
    __shared__ __align__(16) float S[16384];  // 64 KB: A [0,8192) persistent | Bs [8192,16384)
    __shared__ float zz_s[BM];
    __shared__ float tmp2[64];
    __shared__ float pD[BM][8];
    __shared__ int   pI[BM][8];

    float (*A)[BM]        = (float (*)[BM])S;                // [256][32], live to end of main loop
    float (*Bs)[KB][SECW] = (float (*)[KB][SECW])(S + 8192); // [2][8][512] = 32 KB
    float (*redD)[64]     = (float (*)[64])S;                // aliases A (dead) for final reduce
    int   (*redI)[64]     = (int   (*)[64])(S + 2048);

    const int t    = threadIdx.x;
    const int lane = t & 63;
    const int wv   = t >> 6;                            // wave id 0..3
    const int n0   = blockIdx.x * BM;
    const int b    = n0 >> 12;
    const int h    = (n0 >> 6) & 63;
    const int w0   = n0 & 63;                           // 0 or 32

    // stage one KB x 512 tile of W_T into Bs[nb]: 8 rows x 2 halves; 4 instrs/thread,
    // each wave-instr writes 1 KB contiguous (wave-uniform base + lane*16B)
    auto stage = [&](int ssec, int skc, int nb) {
#pragma unroll
        for (int v = 0; v < 4; v++) {
            const int s_  = v * 4 + wv;                  // 0..15
            const int r_  = s_ >> 1;                     // row 0..7 (uniform per wave)
            const int hf_ = s_ & 1;                      // half 0/1 (uniform per wave)
            const float* g_ = WT + (size_t)(skc * KB + r_) * NE + ssec * SECW + hf_ * 256 + lane * 4;
            __builtin_amdgcn_global_load_lds(
                (const __attribute__((address_space(1))) void*)g_,
                (__attribute__((address_space(3))) void*)(&Bs[nb][r_][hf_ * 256]),
                16, 0, 0);
        }
    };

    // ---- stage A: zf_tile[c][q] = z[b, c, h, w0+q]; coalesced float4 ----
    const float* zb = z + (size_t)b * (CDIM * HDIM * WDIM) + (size_t)h * WDIM + w0;
#pragma unroll
    for (int v = 0; v < 8; v++) {
        int idx4 = v * 256 + t;
        int c  = idx4 >> 3;
        int w4 = idx4 & 7;
        *(float4*)(&A[c][w4 * 4]) = *(const float4*)(zb + (size_t)c * (HDIM * WDIM) + w4 * 4);
    }
    // tile0 -> buf0 issued early: its latency hides under the zz phase
    stage(0, 0, 0);
    __syncthreads();   // A writes + tile0 drained

    // ---- zz per query, replicating numpy pairwise (two 128-blocks, 8 accumulators) ----
    if (t < 64) {
        int q = t >> 1, base = (t & 1) * 128;
        float r[8];
#pragma unroll
        for (int j = 0; j < 8; j++) { float x = A[base + j][q]; r[j] = __fmul_rn(x, x); }
        for (int i = 8; i < 128; i += 8) {
#pragma unroll
            for (int j = 0; j < 8; j++) { float x = A[base + i + j][q]; r[j] = __fadd_rn(r[j], __fmul_rn(x, x)); }
        }
        tmp2[t] = __fadd_rn(__fadd_rn(__fadd_rn(r[0], r[1]), __fadd_rn(r[2], r[3])),
                            __fadd_rn(__fadd_rn(r[4], r[5]), __fadd_rn(r[6], r[7])));
    }
    __syncthreads();
    if (t < BM) zz_s[t] = __fadd_rn(tmp2[2 * t], tmp2[2 * t + 1]);
    // zz_s becomes visible to all waves via the kc-loop barriers before first use (sec0 epilogue)

    const int tx = t & 63;               // 0..63: code-groups (2x4 codes each)
    const int q0 = wv * 8;               // 8 queries per wave; A[k][q0..q0+7] broadcast reads

    float bestD[8]; int bestI[8];
#pragma unroll
    for (int i = 0; i < 8; i++) { bestD[i] = 3.0e38f; bestI[i] = 0; }

    for (int sec = 0; sec < 2; sec++) {
        float acc[8][8];
#pragma unroll
        for (int i = 0; i < 8; i++)
#pragma unroll
            for (int j = 0; j < 8; j++) acc[i][j] = 0.0f;

        for (int kc = 0; kc < 32; kc++) {
            const int cur = kc & 1;
            // stage next B tile into the other buffer (drained by this kc's barrier)
            {
                int nkc = kc + 1, nsec = sec;
                if (nkc == 32) { nkc = 0; nsec++; }
                if (nsec < 2) stage(nsec, nkc, cur ^ 1);
            }
            const int kb = kc * KB;
            // compute KB k-steps; all operands from LDS (in-order DS -> fine lgkmcnt);
            // k-order over the full loop is sequential 0..255 (bit-identical acc)
#pragma unroll
            for (int k2 = 0; k2 < KB; k2++) {
                const int k = kb + k2;
                const float4 b4a = *(const float4*)(&Bs[cur][k2][tx * 4]);
                const float4 b4b = *(const float4*)(&Bs[cur][k2][256 + tx * 4]);
                const float4 a40 = *(const float4*)(&A[k][q0]);        // broadcast
                const float4 a41 = *(const float4*)(&A[k][q0 + 4]);    // broadcast
                float avv[8] = {a40.x, a40.y, a40.z, a40.w, a41.x, a41.y, a41.z, a41.w};
                float bvv[8] = {b4a.x, b4a.y, b4a.z, b4a.w, b4b.x, b4b.y, b4b.z, b4b.w};
#pragma unroll
                for (int i = 0; i < 8; i++)
#pragma unroll
                    for (int j = 0; j < 8; j++)
                        acc[i][j] = __fmaf_rn(avv[i], bvv[j], acc[i][j]);
            }
            __syncthreads();   // all waves done with Bs[cur]; next tile drained
        }

        // epilogue: d = fl(fl(zz+ee) - 2m), running argmin.
        // Thread-local e scan ascending (group a then b, sec0 before sec1) +
        // strict <  ==  reference first-min tie rule.
        const int e0a = sec * SECW + tx * 4;
        const int e0b = e0a + 256;
        float4 eeA = *(const float4*)(ee + e0a);
        float4 eeB = *(const float4*)(ee + e0b);
        float eva[4] = {eeA.x, eeA.y, eeA.z, eeA.w};
        float evb[4] = {eeB.x, eeB.y, eeB.z, eeB.w};
#pragma unroll
        for (int i = 0; i < 8; i++) {
            float zzq = zz_s[q0 + i];
#pragma unroll
            for (int j = 0; j < 4; j++) {
                float s = __fadd_rn(zzq, eva[j]);
                float d = __fsub_rn(s, __fadd_rn(acc[i][j], acc[i][j]));
                if (d < bestD[i]) { bestD[i] = d; bestI[i] = e0a + j; }
            }
#pragma unroll
            for (int j = 0; j < 4; j++) {
                float s = __fadd_rn(zzq, evb[j]);
                float d = __fsub_rn(s, __fadd_rn(acc[i][4 + j], acc[i][4 + j]));
                if (d < bestD[i]) { bestD[i] = d; bestI[i] = e0b + j; }
            }
        }
    }

    // ---- cross-thread argmin reduce (lexicographic: min d, then min idx) ----
    __syncthreads();                   // A no longer read; reuse as redD/redI
#pragma unroll
    for (int i = 0; i < 8; i++) { redD[q0 + i][tx] = bestD[i]; redI[q0 + i][tx] = bestI[i]; }
    __syncthreads();
    {
        int q = t >> 3, s8 = t & 7;
        float bd = redD[q][s8 * 8]; int bi = redI[q][s8 * 8];
#pragma unroll
        for (int u = 1; u < 8; u++) {
            float d2 = redD[q][s8 * 8 + u]; int i2 = redI[q][s8 * 8 + u];
            if (d2 < bd || (d2 == bd && i2 < bi)) { bd = d2; bi = i2; }
        }
        pD[q][s8] = bd; pI[q][s8] = bi;
    }
    __syncthreads();
    if (t < BM) {
        float bd = pD[t][0]; int bi = pI[t][0];
#pragma unroll
        for (int u = 1; u < 8; u++) {
            float d2 = pD[t][u]; int i2 = pI[t][u];
            if (d2 < bd || (d2 == bd && i2 < bi)) { bd = d2; bi = i2; }
        }
        out_idx[n0 + t] = (float)bi;
        atomicAdd(&hist[bi], 1);
    }
}

// ---- k4: gather z_q, straight-through output, loss partials ----
__global__ void vq_gather(const float* __restrict__ z, const float* __restrict__ W,
                          const float* __restrict__ idxf, float* __restrict__ zq_out,
                          double* __restrict__ loss_part) {
    const int gid = blockIdx.x * 256 + threadIdx.x;  // 0..4194303 (grid=16384)
    const int w4 = gid & 15;
    const int r  = gid >> 4;         // 0..262143
    const int h  = r & 63;
    const int c  = (r >> 6) & 255;
    const int b  = r >> 14;
    const size_t off = (((size_t)(b * CDIM + c) * HDIM + h) * WDIM) + w4 * 4;
    const float4 zp = *(const float4*)(z + off);
    const int n = b * 4096 + h * 64 + w4 * 4;

    float zpv[4] = {zp.x, zp.y, zp.z, zp.w};
    float ov[4];
    double ls = 0.0;
#pragma unroll
    for (int l = 0; l < 4; l++) {
        int idx = (int)idxf[n + l];
        float zq = W[(size_t)idx * CDIM + c];
        float t1 = __fsub_rn(zq, zpv[l]);       // fl(z_q - zp)
        ov[l] = __fadd_rn(zpv[l], t1);          // fl(zp + fl(z_q - zp))
        ls += (double)t1 * (double)t1;
    }
    float4 o = {ov[0], ov[1], ov[2], ov[3]};
    *(float4*)(zq_out + off) = o;

    // wave + block reduce, one atomic per block into 256 slots
#pragma unroll
    for (int s = 32; s > 0; s >>= 1) ls += __shfl_down(ls, s, 64);
    __shared__ double wsum[4];
    if ((threadIdx.x & 63) == 0) wsum[threadIdx.x >> 6] = ls;
    __syncthreads();
    if (threadIdx.x == 0) {
        double v = wsum[0] + wsum[1] + wsum[2] + wsum[3];
        atomicAdd(&loss_part[blockIdx.x & 255], v);
    }
}

// ---- k5: finalize loss + perplexity ----
__global__ void vq_final(const double* __restrict__ loss_part, const int* __restrict__ hist,
                         float* __restrict__ d_out) {
    __shared__ double s1[256], s2[256];
    const int t = threadIdx.x;
    double v = loss_part[t];
    double pv = 0.0;
#pragma unroll
    for (int j = 0; j < 4; j++) {
        int cnt = hist[t * 4 + j];
        double em = (double)cnt / 65536.0;
        pv += em * log(em + 1e-10);
    }
    s1[t] = v; s2[t] = pv;
    __syncthreads();
    for (int st = 128; st > 0; st >>= 1) {
        if (t < st) { s1[t] += s1[t + st]; s2[t] += s2[t + st]; }
        __syncthreads();
    }
    if (t == 0) {
        float m = (float)(s1[0] / 16777216.0);
        d_out[0] = 1.25f * m;                    // mean + 0.25*mean
        d_out[PERP_OFF] = (float)exp(-s2[0]);
    }
}

extern "C" void kernel_launch(void* const* d_in, const int* in_sizes, int n_in,
                              void* d_out, int out_size, void* d_ws, size_t ws_size,
                              hipStream_t stream) {
    const float* z = (const float*)d_in[0];
    const float* W = (const float*)d_in[1];
    float* out = (float*)d_out;

    float*  ee        = (float*)((char*)d_ws + WS_EE_OFF);
    int*    hist      = (int*)((char*)d_ws + WS_HIST_OFF);
    double* loss_part = (double*)((char*)d_ws + WS_LOSS_OFF);
    float*  WT        = (float*)((char*)d_ws + WS_WT_OFF);   // 1 MB k-major codebook

    vq_prep<<<4, 256, 0, stream>>>(W, ee, hist, loss_part);
    vq_transpose<<<64, 256, 0, stream>>>(W, WT);
    vq_argmin<<<NQ / BM, 256, 0, stream>>>(z, WT, ee, out + IDX_OFF, hist);
    vq_gather<<<(NQ * CDIM / 4) / 256, 256, 0, stream>>>(z, W, out + IDX_OFF, out + ZQ_OFF, loss_part);
    vq_final<<<1, 256, 0, stream>>>(loss_part, hist, out);
}

// Round 10
// 514.559 us; speedup vs baseline: 1.4289x; 1.2072x over previous
//
#include <hip/hip_runtime.h>

// Problem constants
#define BATCH 16
#define CDIM  256   // embedding dim / K of the GEMM
#define HDIM  64
#define WDIM  64
#define NQ    65536   // BATCH*HDIM*WDIM
#define NE    1024    // codebook size
#define BM    32      // queries per block in argmin kernel
#define KB    8       // k-rows staged per B tile (double-buffered)
#define SECW  512     // codes per section (2 sections)

// d_out layout (floats): [0]=loss, [1..16777216]=z_q_st, [16777217..16842752]=idx, [16842753]=perplexity
#define ZQ_OFF   1
#define IDX_OFF  16777217
#define PERP_OFF 16842753

// ws layout: ee float[1024] @0 ; hist int[1024] @4096 ; loss_part double[256] @8192 ; W_T float[256][1024] @16384
#define WS_EE_OFF    0
#define WS_HIST_OFF  4096
#define WS_LOSS_OFF  8192
#define WS_WT_OFF    16384

// ---- numpy-pairwise sum-of-squares over 128 contiguous floats (8-accumulator tree) ----
__device__ __forceinline__ float pw128_sq(const float* __restrict__ p) {
    float r[8];
#pragma unroll
    for (int j = 0; j < 8; j++) r[j] = __fmul_rn(p[j], p[j]);
#pragma unroll
    for (int i = 8; i < 128; i += 8) {
#pragma unroll
        for (int j = 0; j < 8; j++) r[j] = __fadd_rn(r[j], __fmul_rn(p[i + j], p[i + j]));
    }
    return __fadd_rn(__fadd_rn(__fadd_rn(r[0], r[1]), __fadd_rn(r[2], r[3])),
                     __fadd_rn(__fadd_rn(r[4], r[5]), __fadd_rn(r[6], r[7])));
}

// ---- k1: codebook norms (numpy-pairwise), zero hist + loss accumulators ----
__global__ void vq_prep(const float* __restrict__ W, float* __restrict__ ee,
                        int* __restrict__ hist, double* __restrict__ loss_part) {
    int t = blockIdx.x * 256 + threadIdx.x;   // 0..1023, grid=4
    hist[t] = 0;
    if (t < 256) loss_part[t] = 0.0;
    const float* p = W + (size_t)t * CDIM;
    ee[t] = __fadd_rn(pw128_sq(p), pw128_sq(p + 128));
}

// ---- k1b: transpose W [1024][256] -> W_T [256][1024] (bitwise copy, enables linear
//           global_load_lds staging of k-major B tiles in vq_argmin) ----
__global__ void vq_transpose(const float* __restrict__ W, float* __restrict__ WT) {
    __shared__ float T[64][65];               // +1 pad: transposed reads 2-way (free)
    const int e0 = (blockIdx.x & 15) * 64;
    const int k0 = (blockIdx.x >> 4) * 64;
    const int r  = threadIdx.x >> 4;          // 0..15
    const int c4 = threadIdx.x & 15;          // 0..15
#pragma unroll
    for (int s = 0; s < 4; s++) {
        float4 v = *(const float4*)(W + (size_t)(e0 + s * 16 + r) * CDIM + k0 + c4 * 4);
        T[s * 16 + r][c4 * 4 + 0] = v.x;
        T[s * 16 + r][c4 * 4 + 1] = v.y;
        T[s * 16 + r][c4 * 4 + 2] = v.z;
        T[s * 16 + r][c4 * 4 + 3] = v.w;
    }
    __syncthreads();
#pragma unroll
    for (int s = 0; s < 4; s++) {
        float4 o;
        o.x = T[c4 * 4 + 0][s * 16 + r];
        o.y = T[c4 * 4 + 1][s * 16 + r];
        o.z = T[c4 * 4 + 2][s * 16 + r];
        o.w = T[c4 * 4 + 3][s * 16 + r];
        *(float4*)(WT + (size_t)(k0 + s * 16 + r) * NE + e0 + c4 * 4) = o;
    }
}

// ---- k2: fused distance GEMM + argmin ----
// EXACT round-7 kernel (measured 448us, VGPR=88 clean, best verified clean
// config): 2 code sections, acc[8][8]; A on the scalar pipe (s_load via
// readfirstlane-uniform base); B via global_load_lds double-buffered tiles,
// one barrier per kc; (256,2) launch bounds (the only min-waves arg that
// yields a >64-VGPR spill-free allocation on this toolchain — r2/3/5/6/8
// all spilled under arg=4 or with VGPR A-pipelines; r9's pure-DS A was
// LDS-pipe-bound at 512us).
// FMA chain per (q,code) is k=0..255 ascending, identical rounding -> bit-exact.
__global__ __launch_bounds__(256, 2)
void vq_argmin(const float* __restrict__ z, const float* __restrict__ WT,
               const float* __restrict__ ee, float* __restrict__ out_idx,
               int* __restrict__ hist) {
    __shared__ __align__(16) float S[8192];   // 32 KB union: A | Bs dbuf | redD/redI
    __shared__ float zz_s[BM];
    __shared__ float tmp2[64];
    __shared__ float pD[BM][8];
    __shared__ int   pI[BM][8];

    float (*A)[BM]        = (float (*)[BM])S;            // [256][32] (prologue only)
    float (*Bs)[KB][SECW] = (float (*)[KB][SECW])S;      // [2][8][512] = 32 KB (main loop)
    float (*redD)[64]     = (float (*)[64])S;            // [32][64] (final reduce)
    int   (*redI)[64]     = (int   (*)[64])(S + 2048);   // next 8 KB

    const int t    = threadIdx.x;
    const int lane = t & 63;
    const int wv   = t >> 6;                            // wave id 0..3
    const int n0   = blockIdx.x * BM;
    const int b    = n0 >> 12;
    const int h    = (n0 >> 6) & 63;
    const int w0   = n0 & 63;                           // 0 or 32

    // ---- stage A: zf_tile[c][q] = z[b, c, h, w0+q]; coalesced float4 ----
    const float* zb = z + (size_t)b * (CDIM * HDIM * WDIM) + (size_t)h * WDIM + w0;
#pragma unroll
    for (int v = 0; v < 8; v++) {
        int idx4 = v * 256 + t;
        int c  = idx4 >> 3;
        int w4 = idx4 & 7;
        *(float4*)(&A[c][w4 * 4]) = *(const float4*)(zb + (size_t)c * (HDIM * WDIM) + w4 * 4);
    }
    __syncthreads();

    // ---- zz per query, replicating numpy pairwise (two 128-blocks, 8 accumulators) ----
    if (t < 64) {
        int q = t >> 1, base = (t & 1) * 128;
        float r[8];
#pragma unroll
        for (int j = 0; j < 8; j++) { float x = A[base + j][q]; r[j] = __fmul_rn(x, x); }
        for (int i = 8; i < 128; i += 8) {
#pragma unroll
            for (int j = 0; j < 8; j++) { float x = A[base + i + j][q]; r[j] = __fadd_rn(r[j], __fmul_rn(x, x)); }
        }
        tmp2[t] = __fadd_rn(__fadd_rn(__fadd_rn(r[0], r[1]), __fadd_rn(r[2], r[3])),
                            __fadd_rn(__fadd_rn(r[4], r[5]), __fadd_rn(r[6], r[7])));
    }
    __syncthreads();
    if (t < BM) zz_s[t] = __fadd_rn(tmp2[2 * t], tmp2[2 * t + 1]);

    const int tx  = t & 63;                              // 0..63: code-groups (2x4 codes each)
    const int q0  = wv * 8;                              // 8 queries per wave
    const int q0u = __builtin_amdgcn_readfirstlane(q0);  // provably wave-uniform -> SMEM loads
    const float* aG = zb + q0u;                          // A[k][q0+i] = aG[k*4096 + i]

    // stage one KB x 512 tile of W_T into Bs[nb]: 8 rows x 2 halves; 4 instrs/thread,
    // each wave-instr writes 1 KB contiguous (wave-uniform base + lane*16B)
    auto stage = [&](int ssec, int skc, int nb) {
#pragma unroll
        for (int v = 0; v < 4; v++) {
            const int s_  = v * 4 + wv;                  // 0..15
            const int r_  = s_ >> 1;                     // row 0..7 (uniform per wave)
            const int hf_ = s_ & 1;                      // half 0/1 (uniform per wave)
            const float* g_ = WT + (size_t)(skc * KB + r_) * NE + ssec * SECW + hf_ * 256 + lane * 4;
            __builtin_amdgcn_global_load_lds(
                (const __attribute__((address_space(1))) void*)g_,
                (__attribute__((address_space(3))) void*)(&Bs[nb][r_][hf_ * 256]),
                16, 0, 0);
        }
    };

    float bestD[8]; int bestI[8];
#pragma unroll
    for (int i = 0; i < 8; i++) { bestD[i] = 3.0e38f; bestI[i] = 0; }

    // prologue: tile (sec0,kc0) -> buf0 (A region dead; zz reads done pre-barrier)
    stage(0, 0, 0);
    __syncthreads();   // zz_s visible + tile0 drained (vmcnt(0) in syncthreads)

    for (int sec = 0; sec < 2; sec++) {
        float acc[8][8];
#pragma unroll
        for (int i = 0; i < 8; i++)
#pragma unroll
            for (int j = 0; j < 8; j++) acc[i][j] = 0.0f;

        for (int kc = 0; kc < 32; kc++) {
            const int cur = kc & 1;
            // stage next B tile into the other buffer (drained by this kc's barrier)
            {
                int nkc = kc + 1, nsec = sec;
                if (nkc == 32) { nkc = 0; nsec++; }
                if (nsec < 2) stage(nsec, nkc, cur ^ 1);
            }
            const int kb = kc * KB;
            // compute KB k-steps; k-order over full loop is sequential 0..255 (bit-identical acc)
#pragma unroll
            for (int k2 = 0; k2 < KB; k2++) {
                const float4 b4a = *(const float4*)(&Bs[cur][k2][tx * 4]);
                const float4 b4b = *(const float4*)(&Bs[cur][k2][256 + tx * 4]);
                const float* ar = aG + (size_t)(kb + k2) * 4096;
                float av[8];
#pragma unroll
                for (int i = 0; i < 8; i++) av[i] = ar[i];   // uniform -> s_load_dwordx8
                float bv[8] = {b4a.x, b4a.y, b4a.z, b4a.w, b4b.x, b4b.y, b4b.z, b4b.w};
#pragma unroll
                for (int i = 0; i < 8; i++)
#pragma unroll
                    for (int j = 0; j < 8; j++)
                        acc[i][j] = __fmaf_rn(av[i], bv[j], acc[i][j]);
            }
            __syncthreads();   // all waves done with Bs[cur]; next tile drained
        }

        // epilogue: d = fl(fl(zz+ee) - 2m), running argmin.
        // Thread-local e scan is ascending (group0 tx*4.. then group1 256+tx*4..,
        // sec0 before sec1) + strict <  ==  reference first-min tie rule.
        const int e0a = sec * SECW + tx * 4;
        const int e0b = e0a + 256;
        float4 eeA = *(const float4*)(ee + e0a);
        float4 eeB = *(const float4*)(ee + e0b);
        float eva[4] = {eeA.x, eeA.y, eeA.z, eeA.w};
        float evb[4] = {eeB.x, eeB.y, eeB.z, eeB.w};
#pragma unroll
        for (int i = 0; i < 8; i++) {
            float zzq = zz_s[q0 + i];
#pragma unroll
            for (int j = 0; j < 4; j++) {
                float s = __fadd_rn(zzq, eva[j]);
                float d = __fsub_rn(s, __fadd_rn(acc[i][j], acc[i][j]));
                if (d < bestD[i]) { bestD[i] = d; bestI[i] = e0a + j; }
            }
#pragma unroll
            for (int j = 0; j < 4; j++) {
                float s = __fadd_rn(zzq, evb[j]);
                float d = __fsub_rn(s, __fadd_rn(acc[i][4 + j], acc[i][4 + j]));
                if (d < bestD[i]) { bestD[i] = d; bestI[i] = e0b + j; }
            }
        }
    }

    // ---- cross-thread argmin reduce (lexicographic: min d, then min idx) ----
    __syncthreads();                   // Bs no longer read; reuse as redD/redI
#pragma unroll
    for (int i = 0; i < 8; i++) { redD[q0 + i][tx] = bestD[i]; redI[q0 + i][tx] = bestI[i]; }
    __syncthreads();
    {
        int q = t >> 3, s8 = t & 7;
        float bd = redD[q][s8 * 8]; int bi = redI[q][s8 * 8];
#pragma unroll
        for (int u = 1; u < 8; u++) {
            float d2 = redD[q][s8 * 8 + u]; int i2 = redI[q][s8 * 8 + u];
            if (d2 < bd || (d2 == bd && i2 < bi)) { bd = d2; bi = i2; }
        }
        pD[q][s8] = bd; pI[q][s8] = bi;
    }
    __syncthreads();
    if (t < BM) {
        float bd = pD[t][0]; int bi = pI[t][0];
#pragma unroll
        for (int u = 1; u < 8; u++) {
            float d2 = pD[t][u]; int i2 = pI[t][u];
            if (d2 < bd || (d2 == bd && i2 < bi)) { bd = d2; bi = i2; }
        }
        out_idx[n0 + t] = (float)bi;
        atomicAdd(&hist[bi], 1);
    }
}

// ---- k4: gather z_q (cooperative coalesced rows), straight-through output, loss ----
// REWRITTEN: old version did 4 scalar scattered W reads per thread (4B used per
// 64-128B line -> ~1-2 GB of L1/L2 line traffic, ~90us). Now: block = 32
// queries (one argmin tile); each wave reads 8 selected codebook rows as
// lane*4 float4 -> ONE coalesced 1 KB read per row (perfect line efficiency,
// W is L2-resident). Rows land in a 32 KB LDS tile with XOR column swizzle
// (c ^ ((row&7)<<2)) so the transposed read phase is only 4-way-conflicted.
// Output phase streams z/zq_out with 128B-segment coalescing (2 segments per
// wave-instr, same efficiency class as the old kernel's accesses).
// Per-element math identical: t1=fl(zq-zp), ov=fl(zp+t1) -> z_q_st bits
// unchanged. Loss partial-sum grouping changes (32 terms/thread vs 4); safe:
// the double sum already tolerates run-to-run atomicAdd ordering noise of the
// same magnitude (~1e-15 rel) with absmax=0.0.
__global__ __launch_bounds__(256, 2)
void vq_gather(const float* __restrict__ z, const float* __restrict__ W,
               const float* __restrict__ idxf, float* __restrict__ zq_out,
               double* __restrict__ loss_part) {
    __shared__ int    idx_s[32];
    __shared__ float  zq_s[32][256];   // 32 KB, XOR-swizzled columns
    __shared__ double wsum[4];

    const int t    = threadIdx.x;
    const int lane = t & 63;
    const int wv   = t >> 6;                  // wave id 0..3
    const int n0   = blockIdx.x * 32;         // 2048 blocks
    const int b    = n0 >> 12;
    const int h    = (n0 >> 6) & 63;
    const int w0   = n0 & 63;                 // 0 or 32

    if (t < 32) idx_s[t] = (int)idxf[n0 + t];
    __syncthreads();

    // gather 32 codebook rows; one coalesced 1 KB read + 1 KB LDS write per row
#pragma unroll
    for (int j = 0; j < 8; j++) {
        const int q   = wv * 8 + j;
        const int idx = idx_s[q];
        float4 v = *(const float4*)(W + (size_t)idx * CDIM + lane * 4);
        *(float4*)(&zq_s[q][(lane * 4) ^ ((q & 7) << 2)]) = v;   // conflict-free write
    }
    __syncthreads();

    // transposed output + loss: thread t -> w = t&31, c = (t>>5)*32 .. +31
    const int w  = t & 31;
    const int cb = (t >> 5) * 32;
    const int sw = (w & 7) << 2;
    const size_t base = (size_t)b * (CDIM * HDIM * WDIM) + (size_t)h * WDIM + w0 + w;
    double ls = 0.0;
#pragma unroll 8
    for (int cc = 0; cc < 32; cc++) {
        const int c = cb + cc;
        const float zq = zq_s[w][c ^ sw];                 // 4-way conflict (cheap)
        const size_t off = base + (size_t)c * (HDIM * WDIM);
        const float zp = z[off];                          // 128B segments across wave
        const float t1 = __fsub_rn(zq, zp);               // fl(z_q - zp)
        zq_out[off] = __fadd_rn(zp, t1);                  // fl(zp + fl(z_q - zp))
        ls += (double)t1 * (double)t1;
    }

    // wave + block reduce, one atomic per block into 256 slots
#pragma unroll
    for (int s = 32; s > 0; s >>= 1) ls += __shfl_down(ls, s, 64);
    if (lane == 0) wsum[wv] = ls;
    __syncthreads();
    if (t == 0) {
        double v = wsum[0] + wsum[1] + wsum[2] + wsum[3];
        atomicAdd(&loss_part[blockIdx.x & 255], v);
    }
}

// ---- k5: finalize loss + perplexity ----
__global__ void vq_final(const double* __restrict__ loss_part, const int* __restrict__ hist,
                         float* __restrict__ d_out) {
    __shared__ double s1[256], s2[256];
    const int t = threadIdx.x;
    double v = loss_part[t];
    double pv = 0.0;
#pragma unroll
    for (int j = 0; j < 4; j++) {
        int cnt = hist[t * 4 + j];
        double em = (double)cnt / 65536.0;
        pv += em * log(em + 1e-10);
    }
    s1[t] = v; s2[t] = pv;
    __syncthreads();
    for (int st = 128; st > 0; st >>= 1) {
        if (t < st) { s1[t] += s1[t + st]; s2[t] += s2[t + st]; }
        __syncthreads();
    }
    if (t == 0) {
        float m = (float)(s1[0] / 16777216.0);
        d_out[0] = 1.25f * m;                    // mean + 0.25*mean
        d_out[PERP_OFF] = (float)exp(-s2[0]);
    }
}

extern "C" void kernel_launch(void* const* d_in, const int* in_sizes, int n_in,
                              void* d_out, int out_size, void* d_ws, size_t ws_size,
                              hipStream_t stream) {
    const float* z = (const float*)d_in[0];
    const float* W = (const float*)d_in[1];
    float* out = (float*)d_out;

    float*  ee        = (float*)((char*)d_ws + WS_EE_OFF);
    int*    hist      = (int*)((char*)d_ws + WS_HIST_OFF);
    double* loss_part = (double*)((char*)d_ws + WS_LOSS_OFF);
    float*  WT        = (float*)((char*)d_ws + WS_WT_OFF);   // 1 MB k-major codebook

    vq_prep<<<4, 256, 0, stream>>>(W, ee, hist, loss_part);
    vq_transpose<<<64, 256, 0, stream>>>(W, WT);
    vq_argmin<<<NQ / BM, 256, 0, stream>>>(z, WT, ee, out + IDX_OFF, hist);
    vq_gather<<<NQ / 32, 256, 0, stream>>>(z, W, out + IDX_OFF, out + ZQ_OFF, loss_part);
    vq_final<<<1, 256, 0, stream>>>(loss_part, hist, out);
}